// Round 2
// baseline (4091.577 us; speedup 1.0000x reference)
//
#include <hip/hip_runtime.h>
#include <math.h>
#include <float.h>

namespace {

constexpr int Bb = 8, Kk = 4, BKn = 32, Dd = 1024, Ff = 4096, Vv = 32000, Tt = 16;
constexpr int NDCHn = 8, DCHn = 128;          // gates d-chunking
constexpr int VCOLSn = 128, NVCHn = 250;      // logits vocab chunking
constexpr int EOSt = 2, PADt = 0;
constexpr float BIGf = 1e9f, EOSSf = 1000.0f;

// ---- workspace layout (float indices) ----
constexpr size_t OFF_XT  = 0;                                  // xT  [D][32]
constexpr size_t OFF_HT  = OFF_XT  + (size_t)Dd * BKn;         // hT  [D][32]
constexpr size_t OFF_HTN = OFF_HT  + (size_t)Dd * BKn;         // hTn [D][32]
constexpr size_t OFF_CA  = OFF_HTN + (size_t)Dd * BKn;         // c   [32][D]
constexpr size_t OFF_CN  = OFF_CA  + (size_t)Dd * BKn;         // c_new [32][D]
constexpr size_t OFF_GP  = OFF_CN  + (size_t)Dd * BKn;         // gate partials [8][32][4096]
constexpr size_t OFF_CS  = OFF_GP  + (size_t)NDCHn * BKn * Ff; // chunk stats [250][32][12]
constexpr size_t OFF_BT  = OFF_CS  + (size_t)NVCHn * BKn * 12; // beam top [32][8]
constexpr size_t OFF_SC  = OFF_BT  + (size_t)BKn * 8;          // scores [32]
constexpr size_t OFF_INT = OFF_SC  + BKn;                      // int region starts
// int offsets within int region
constexpr int IW = 0, ISTOP = 32, IPREV = 40, IBUFA = 72, IBUFB = IBUFA + Bb * Kk * Tt;

__device__ inline void ins4(float v, int id, float tv[4], int ti[4]) {
#pragma unroll
  for (int r = 0; r < 4; r++) {
    bool better = (v > tv[r]) || (v == tv[r] && id < ti[r]);
    if (better) { float fv = tv[r]; int fi = ti[r]; tv[r] = v; ti[r] = id; v = fv; id = fi; }
  }
}

// merge per-lane sorted top-4 lists into wave-global top-4 (desc value, asc idx on ties)
__device__ inline void wave_merge_top4(float tv[4], int ti[4], float ov[4], int oi[4]) {
#pragma unroll
  for (int r = 0; r < 4; r++) {
    float hv = tv[0]; int hi = ti[0];
    float m = hv;
    for (int off = 32; off; off >>= 1) m = fmaxf(m, __shfl_xor(m, off));
    int c = (hv == m) ? hi : 0x7fffffff;
    for (int off = 32; off; off >>= 1) c = min(c, __shfl_xor(c, off));
    if (hv == m && hi == c) {   // this lane's head won: pop
      tv[0] = tv[1]; ti[0] = ti[1];
      tv[1] = tv[2]; ti[1] = ti[2];
      tv[2] = tv[3]; ti[2] = ti[3];
      tv[3] = -FLT_MAX; ti[3] = 0x7fffffff;
    }
    ov[r] = m; oi[r] = c;
  }
}

__global__ __launch_bounds__(256) void initK(const int* __restrict__ words,
    const float* __restrict__ h0, const float* __restrict__ c0,
    const float* __restrict__ E, float* __restrict__ ws) {
  int* wsi = (int*)(ws + OFF_INT);
  if (blockIdx.x < 128) {
    int g = blockIdx.x * 256 + threadIdx.x;   // 0..32767
    int d = g >> 5, bk = g & 31;
    int w0 = words[bk];
    ws[OFF_HT + g] = h0[(size_t)bk * Dd + d];
    ws[OFF_XT + g] = E[(size_t)w0 * Dd + d];
    ws[OFF_CA + g] = c0[g];
  } else {
    int t = threadIdx.x;
    if (t < BKn) {
      ws[OFF_SC + t] = ((t & 3) == 0) ? 0.f : BIGf;
      wsi[IW + t] = words[t];
      wsi[IPREV + t] = 0;
    }
    if (t < Bb) wsi[ISTOP + t] = 0;
    for (int i = t; i < 2 * Bb * Kk * Tt; i += 256) wsi[IBUFA + i] = 0;
  }
}

// gates partial GEMM: Gp[dc][bk][f] = sum_{d in chunk} x[bk][d]*Wx[d][f] + h[bk][d]*Wh[d][f]
__global__ __launch_bounds__(256) void gatesK(const float* __restrict__ Wx,
    const float* __restrict__ Wh, const float* __restrict__ xT,
    const float* __restrict__ hT, float* __restrict__ Gp) {
  int f = blockIdx.x * 256 + threadIdx.x;
  int dc = blockIdx.y;
  float acc[BKn];
#pragma unroll
  for (int i = 0; i < BKn; i++) acc[i] = 0.f;
  int d0 = dc * DCHn;
#pragma unroll 2
  for (int d = d0; d < d0 + DCHn; ++d) {
    float wx = Wx[(size_t)d * Ff + f];
    float wh = Wh[(size_t)d * Ff + f];
    const float* xr = xT + (size_t)d * BKn;
    const float* hr = hT + (size_t)d * BKn;
#pragma unroll
    for (int i = 0; i < BKn; i++) acc[i] = fmaf(xr[i], wx, fmaf(hr[i], wh, acc[i]));
  }
  float* out = Gp + ((size_t)dc * BKn) * Ff + f;
#pragma unroll
  for (int i = 0; i < BKn; i++) out[(size_t)i * Ff] = acc[i];
}

__global__ __launch_bounds__(256) void lstmK(const float* __restrict__ bvec,
    const float* __restrict__ Gp, const float* __restrict__ cA,
    float* __restrict__ cN, float* __restrict__ hTn) {
  int g = blockIdx.x * 256 + threadIdx.x;   // 0..32767
  int bk = g >> 10, dc = g & 1023;
  float gi = bvec[dc], gf = bvec[Dd + dc], gg = bvec[2 * Dd + dc], go = bvec[3 * Dd + dc];
#pragma unroll
  for (int p = 0; p < NDCHn; p++) {
    const float* row = Gp + ((size_t)p * BKn + bk) * Ff;
    gi += row[dc]; gf += row[Dd + dc]; gg += row[2 * Dd + dc]; go += row[3 * Dd + dc];
  }
  float si = 1.f / (1.f + expf(-gi));
  float sf = 1.f / (1.f + expf(-gf));
  float so = 1.f / (1.f + expf(-go));
  float tg = tanhf(gg);
  float c  = cA[g];
  float cn = sf * c + si * tg;
  float hn = so * tanhf(cn);
  cN[g] = cn;
  hTn[(size_t)dc * BKn + bk] = hn;
}

// logits for 128 vocab cols, d split across 2 half-blocks, LDS reduce, fused chunk stats
__global__ __launch_bounds__(256) void logitsK(const float* __restrict__ Wo,
    const float* __restrict__ bo, const float* __restrict__ hTn,
    float* __restrict__ csOut) {
  __shared__ float sd[2][BKn][VCOLSn];
  int tid = threadIdx.x;
  int half = tid >> 7;
  int col = tid & 127;
  int v = blockIdx.x * VCOLSn + col;
  float acc[BKn];
#pragma unroll
  for (int i = 0; i < BKn; i++) acc[i] = 0.f;
  int d0 = half * 512;
#pragma unroll 4
  for (int d = d0; d < d0 + 512; ++d) {
    float wv = Wo[(size_t)d * Vv + v];
    const float* hr = hTn + (size_t)d * BKn;
#pragma unroll
    for (int i = 0; i < BKn; i++) acc[i] = fmaf(hr[i], wv, acc[i]);
  }
#pragma unroll
  for (int i = 0; i < BKn; i++) sd[half][i][col] = acc[i];
  __syncthreads();
  if (tid >= 128) return;
  int lane = tid & 63;
  int wv_ = tid >> 6;                         // wave 0 -> beams 0..15, wave 1 -> 16..31
  int i0 = blockIdx.x * VCOLSn + lane;
  int i1 = i0 + 64;
  float b0 = bo[i0], b1 = bo[i1];
  for (int bb = 0; bb < 16; ++bb) {
    int bk = wv_ * 16 + bb;
    float v0 = sd[0][bk][lane]      + sd[1][bk][lane]      + b0;
    float v1 = sd[0][bk][lane + 64] + sd[1][bk][lane + 64] + b1;
    float m = fmaxf(v0, v1);
    for (int off = 32; off; off >>= 1) m = fmaxf(m, __shfl_xor(m, off));
    float se = expf(v0 - m) + expf(v1 - m);
    for (int off = 32; off; off >>= 1) se += __shfl_xor(se, off);
    float tv[4]; int ti[4];
#pragma unroll
    for (int r = 0; r < 4; r++) { tv[r] = -FLT_MAX; ti[r] = 0x7fffffff; }
    ins4(v0, i0, tv, ti);
    ins4(v1, i1, tv, ti);
    float ov[4]; int oi[4];
    wave_merge_top4(tv, ti, ov, oi);
    if (lane == 0) {
      float* p = csOut + ((size_t)blockIdx.x * BKn + bk) * 12;
      p[0] = m; p[1] = se;
#pragma unroll
      for (int r = 0; r < 4; r++) { p[2 + r] = ov[r]; p[6 + r] = __int_as_float(oi[r]); }
    }
  }
}

// per-beam merge of 250 chunk stats -> lse + global top-4 (p-values + vocab ids)
__global__ __launch_bounds__(64) void reduceK(const float* __restrict__ cs,
                                              float* __restrict__ bt) {
  int bk = blockIdx.x;
  int lane = threadIdx.x;
  float cm[4], csum[4]; bool valid[4];
  float tv[4]; int ti[4];
#pragma unroll
  for (int r = 0; r < 4; r++) { tv[r] = -FLT_MAX; ti[r] = 0x7fffffff; }
  float lm = -FLT_MAX;
#pragma unroll
  for (int q = 0; q < 4; q++) {
    int c = lane + 64 * q;
    valid[q] = c < NVCHn;
    if (valid[q]) {
      const float* p = cs + ((size_t)c * BKn + bk) * 12;
      cm[q] = p[0]; csum[q] = p[1];
      lm = fmaxf(lm, cm[q]);
#pragma unroll
      for (int r = 0; r < 4; r++) ins4(p[2 + r], __float_as_int(p[6 + r]), tv, ti);
    } else { cm[q] = -FLT_MAX; csum[q] = 0.f; }
  }
  float M = lm;
  for (int off = 32; off; off >>= 1) M = fmaxf(M, __shfl_xor(M, off));
  float ls = 0.f;
#pragma unroll
  for (int q = 0; q < 4; q++) if (valid[q]) ls += csum[q] * expf(cm[q] - M);
  for (int off = 32; off; off >>= 1) ls += __shfl_xor(ls, off);
  float lse = M + logf(ls);
  float ov[4]; int oi[4];
  wave_merge_top4(tv, ti, ov, oi);
  if (lane == 0) {
    float* o = bt + (size_t)bk * 8;
#pragma unroll
    for (int r = 0; r < 4; r++) { o[r] = lse - ov[r]; o[4 + r] = __int_as_float(oi[r]); }
  }
}

// exact beam-search selection + EOS logic + buf ping-pong
__global__ __launch_bounds__(64) void selK(float* __restrict__ ws, int step) {
  __shared__ int s_tok[BKn], s_prevb[BKn];
  int* wsi = (int*)(ws + OFF_INT);
  int tid = threadIdx.x;
  if (tid < Bb) {
    int b = tid;
    int st = wsi[ISTOP + b];
    float sc[4];
#pragma unroll
    for (int k = 0; k < 4; k++) sc[k] = ws[OFF_SC + b * 4 + k];
    float cval[16]; int ctok[16];
#pragma unroll
    for (int kb = 0; kb < 4; kb++) {
      const float* btp = ws + OFF_BT + (size_t)(b * 4 + kb) * 8;
#pragma unroll
      for (int r = 0; r < 4; r++) {
        cval[kb * 4 + r] = btp[r] + sc[kb];
        ctok[kb * 4 + r] = __float_as_int(btp[4 + r]);
      }
    }
    float selS[4]; int selW[4], prevK[4];
    int usedMask = 0;
#pragma unroll
    for (int r = 0; r < 4; r++) {
      int best = -1; float bv = FLT_MAX;
#pragma unroll
      for (int t = 0; t < 16; t++) {
        if (!((usedMask >> t) & 1) && cval[t] < bv) { bv = cval[t]; best = t; }
      }
      usedMask |= 1 << best;
      selS[r] = bv; selW[r] = ctok[best]; prevK[r] = best >> 2;
    }
    bool eos[4];
#pragma unroll
    for (int r = 0; r < 4; r++) eos[r] = (selW[r] == EOSt);
    bool first = eos[0] && !st;
#pragma unroll
    for (int r = 0; r < 4; r++) if (eos[r] && !first && !st) selS[r] = EOSSf;
#pragma unroll
    for (int k = 0; k < 4; k++) {
      int tok = st ? PADt : (first ? EOSt : selW[k]);
      int pb  = st ? k : prevK[k];
      s_tok[b * 4 + k] = tok;
      s_prevb[b * 4 + k] = pb;
      if (!st) { ws[OFF_SC + b * 4 + k] = selS[k]; wsi[IW + b * 4 + k] = selW[k]; }
      wsi[IPREV + b * 4 + k] = prevK[k];
    }
    wsi[ISTOP + b] = (st || first) ? 1 : 0;
  }
  __syncthreads();
  const int* br = wsi + (((step & 1) == 0) ? IBUFA : IBUFB);
  int* bw = wsi + (((step & 1) == 0) ? IBUFB : IBUFA);
#pragma unroll
  for (int i = 0; i < 8; i++) {
    int e = tid + 64 * i;                 // 0..511
    int bkk = e >> 4, t = e & 15;
    int pb = s_prevb[bkk];
    int src = ((bkk & ~3) | pb) * Tt + t;
    int val = br[src];
    if (t == step) val = s_tok[bkk];
    bw[e] = val;
  }
}

// reorder h/c by prev, gather next-step embeddings
__global__ __launch_bounds__(256) void prepK(const float* __restrict__ E,
                                             float* __restrict__ ws) {
  int* wsi = (int*)(ws + OFF_INT);
  int g = blockIdx.x * 256 + threadIdx.x;   // 0..32767
  int d = g >> 5, bk = g & 31;
  int src = (bk & ~3) | wsi[IPREV + bk];
  ws[OFF_HT + g] = ws[OFF_HTN + (size_t)d * BKn + src];
  int wt = wsi[IW + bk];
  ws[OFF_XT + g] = E[(size_t)wt * Dd + d];
  int bk2 = g >> 10, d2 = g & 1023;
  int src2 = (bk2 & ~3) | wsi[IPREV + bk2];
  ws[OFF_CA + g] = ws[OFF_CN + (size_t)src2 * Dd + d2];
}

// Output is read by the harness as float32 (non-bf16 outputs -> float*).
// Write token ids as float VALUES, scores as floats.
__global__ __launch_bounds__(256) void outK(const float* __restrict__ ws,
                                            float* __restrict__ out) {
  const int* wsi = (const int*)(ws + OFF_INT);
  int g = blockIdx.x * 256 + threadIdx.x;
  if (g < Bb * Kk * Tt) {
    out[g] = (float)wsi[IBUFA + g];               // final buf lives in A after 16 steps
  } else if (g < Bb * Kk * Tt + BKn) {
    out[g] = ws[OFF_SC + (g - Bb * Kk * Tt)];
  }
}

} // namespace

extern "C" void kernel_launch(void* const* d_in, const int* in_sizes, int n_in,
                              void* d_out, int out_size, void* d_ws, size_t ws_size,
                              hipStream_t stream) {
  (void)in_sizes; (void)n_in; (void)out_size; (void)ws_size;
  const int*   words = (const int*)d_in[0];
  const float* h0 = (const float*)d_in[1];
  const float* c0 = (const float*)d_in[2];
  const float* E  = (const float*)d_in[3];
  const float* Wx = (const float*)d_in[4];
  const float* Wh = (const float*)d_in[5];
  const float* bv = (const float*)d_in[6];
  const float* Wo = (const float*)d_in[7];
  const float* bo = (const float*)d_in[8];
  float* ws = (float*)d_ws;
  float* xT  = ws + OFF_XT;
  float* hT  = ws + OFF_HT;
  float* hTn = ws + OFF_HTN;
  float* cA  = ws + OFF_CA;
  float* cN  = ws + OFF_CN;
  float* Gp  = ws + OFF_GP;
  float* cs  = ws + OFF_CS;
  float* bt  = ws + OFF_BT;

  initK<<<129, 256, 0, stream>>>(words, h0, c0, E, ws);
  for (int j = 0; j < Tt; j++) {
    gatesK<<<dim3(16, 8), 256, 0, stream>>>(Wx, Wh, xT, hT, Gp);
    lstmK<<<128, 256, 0, stream>>>(bv, Gp, cA, cN, hTn);
    logitsK<<<250, 256, 0, stream>>>(Wo, bo, hTn, cs);
    reduceK<<<32, 64, 0, stream>>>(cs, bt);
    selK<<<1, 64, 0, stream>>>(ws, j);
    prepK<<<128, 256, 0, stream>>>(E, ws);
  }
  outK<<<3, 256, 0, stream>>>(ws, (float*)d_out);
}

// Round 3
// 2328.508 us; speedup vs baseline: 1.7572x; 1.7572x over previous
//
#include <hip/hip_runtime.h>
#include <math.h>
#include <float.h>

namespace {

constexpr int Bb = 8, Kk = 4, BKn = 32, Dd = 1024, Ff = 4096, Vv = 32000, Tt = 16;
constexpr int GDS = 32, GDC = 32;        // gates d-split / d-chunk  (32*32 = 1024)
constexpr int LDSP = 8, LDC = 128;       // logits d-split / d-chunk (8*128 = 1024)
constexpr int NVCH = 250;                // logits vocab chunks of 128
constexpr int EOSt = 2, PADt = 0;
constexpr float BIGf = 1e9f, EOSSf = 1000.0f;

// ---- workspace layout (float indices) ----
constexpr size_t OFF_HTN = 0;                                   // hTn [1024][32]
constexpr size_t OFF_CB0 = OFF_HTN + (size_t)Dd * BKn;          // c ping [32][1024]
constexpr size_t OFF_CB1 = OFF_CB0 + (size_t)BKn * Dd;          // c pong
constexpr size_t OFF_GP  = OFF_CB1 + (size_t)BKn * Dd;          // gate partials [32][32][4096]
constexpr size_t OFF_PL  = OFF_GP  + (size_t)GDS * BKn * Ff;    // logit partials [8][4][32000][8]
constexpr size_t OFF_CS  = OFF_PL  + (size_t)LDSP * 4 * Vv * 8; // chunk stats [250][32][12]
constexpr size_t OFF_SC  = OFF_CS  + (size_t)NVCH * BKn * 12;   // scores [32]
constexpr size_t OFF_INT = OFF_SC  + BKn;                       // int region
constexpr int IW = 0, ISTOP = 32, IPREV = 40, IBUFA = 72, IBUFB = IBUFA + Bb * Kk * Tt;

__device__ inline void ins4(float v, int id, float tv[4], int ti[4]) {
#pragma unroll
  for (int r = 0; r < 4; r++) {
    bool better = (v > tv[r]) || (v == tv[r] && id < ti[r]);
    if (better) { float fv = tv[r]; int fi = ti[r]; tv[r] = v; ti[r] = id; v = fv; id = fi; }
  }
}

// merge per-lane sorted top-4 into group-global top-4. STARTOFF=32 -> 64-lane wave,
// STARTOFF=16 -> independent 32-lane halves.
template <int STARTOFF>
__device__ inline void merge_top4(float tv[4], int ti[4], float ov[4], int oi[4]) {
#pragma unroll
  for (int r = 0; r < 4; r++) {
    float hv = tv[0]; int hi = ti[0];
    float m = hv;
    for (int off = STARTOFF; off; off >>= 1) m = fmaxf(m, __shfl_xor(m, off));
    int c = (hv == m) ? hi : 0x7fffffff;
    for (int off = STARTOFF; off; off >>= 1) c = min(c, __shfl_xor(c, off));
    if (hv == m && hi == c) {   // this lane's head won: pop
      tv[0] = tv[1]; ti[0] = ti[1];
      tv[1] = tv[2]; ti[1] = ti[2];
      tv[2] = tv[3]; ti[2] = ti[3];
      tv[3] = -FLT_MAX; ti[3] = 0x7fffffff;
    }
    ov[r] = m; oi[r] = c;
  }
}

__global__ __launch_bounds__(256) void initK(const int* __restrict__ words,
    const float* __restrict__ h0, const float* __restrict__ c0,
    float* __restrict__ ws) {
  int* wsi = (int*)(ws + OFF_INT);
  if (blockIdx.x < 128) {
    int g = blockIdx.x * 256 + threadIdx.x;   // 0..32767
    int d = g >> 5, bk = g & 31;
    ws[OFF_HTN + g] = h0[(size_t)bk * Dd + d];   // transpose to [d][bk]
    ws[OFF_CB0 + g] = c0[g];                     // [32][1024] linear
  } else {
    int t = threadIdx.x;
    if (t < BKn) {
      ws[OFF_SC + t] = ((t & 3) == 0) ? 0.f : BIGf;
      wsi[IW + t] = words[t];
      wsi[IPREV + t] = t & 3;                    // identity gather for step 0
    }
    if (t < Bb) wsi[ISTOP + t] = 0;
    for (int i = t; i < 2 * Bb * Kk * Tt; i += 256) wsi[IBUFA + i] = 0;
  }
}

// gates partial GEMM. Gathers x=E[w] and h=hTn[.][src] into LDS directly.
// grid (16, 32): x = 256-col tile of f, y = d-chunk of 32.
__global__ __launch_bounds__(256) void gatesK(const float* __restrict__ Wx,
    const float* __restrict__ Wh, const float* __restrict__ E,
    const float* __restrict__ hTn, const int* __restrict__ wsi,
    float* __restrict__ Gp) {
  __shared__ float xs[GDC][BKn], hs[GDC][BKn];
  int tid = threadIdx.x;
  int d0 = blockIdx.y * GDC;
  {
    int bk = tid & 31, dq = tid >> 5;           // dq 0..7, 4 d each
    int w = wsi[IW + bk];
    int src = (bk & ~3) | wsi[IPREV + bk];
    const float* Erow = E + (size_t)w * Dd + d0;
#pragma unroll
    for (int k = 0; k < 4; k++) {
      int d = dq * 4 + k;
      xs[d][bk] = Erow[d];
      hs[d][bk] = hTn[(size_t)(d0 + d) * BKn + src];
    }
  }
  __syncthreads();
  int ct = tid & 63, bg = tid >> 6;
  int f0 = blockIdx.x * 256 + ct * 4;
  float acc[4][8];
#pragma unroll
  for (int c = 0; c < 4; c++)
#pragma unroll
    for (int i = 0; i < 8; i++) acc[c][i] = 0.f;
#pragma unroll 4
  for (int d = 0; d < GDC; ++d) {
    float4 wx = *(const float4*)(Wx + (size_t)(d0 + d) * Ff + f0);
    float4 wh = *(const float4*)(Wh + (size_t)(d0 + d) * Ff + f0);
    float4 xlo = *(const float4*)&xs[d][bg * 8];
    float4 xhi = *(const float4*)&xs[d][bg * 8 + 4];
    float4 hlo = *(const float4*)&hs[d][bg * 8];
    float4 hhi = *(const float4*)&hs[d][bg * 8 + 4];
    float xv[8] = {xlo.x, xlo.y, xlo.z, xlo.w, xhi.x, xhi.y, xhi.z, xhi.w};
    float hv[8] = {hlo.x, hlo.y, hlo.z, hlo.w, hhi.x, hhi.y, hhi.z, hhi.w};
    float wxc[4] = {wx.x, wx.y, wx.z, wx.w};
    float whc[4] = {wh.x, wh.y, wh.z, wh.w};
#pragma unroll
    for (int c = 0; c < 4; c++)
#pragma unroll
      for (int i = 0; i < 8; i++)
        acc[c][i] = fmaf(xv[i], wxc[c], fmaf(hv[i], whc[c], acc[c][i]));
  }
#pragma unroll
  for (int i = 0; i < 8; i++) {
    int bk = bg * 8 + i;
    float4 o = {acc[0][i], acc[1][i], acc[2][i], acc[3][i]};
    *(float4*)(Gp + ((size_t)blockIdx.y * BKn + bk) * Ff + f0) = o;
  }
}

// reduce 32 gate partials + bias -> nonlinearity; gathers c by prev; writes c_new, hTn.
// grid (32, 4): x = beam, y = quarter of dc. 64 threads, 1 float4 of dc each.
__global__ __launch_bounds__(64) void lstmK(const float* __restrict__ bvec,
    const float* __restrict__ Gp, const float* __restrict__ cPrev,
    const int* __restrict__ wsi, float* __restrict__ cNew,
    float* __restrict__ hTn) {
  int bk = blockIdx.x;
  int dc = blockIdx.y * 256 + threadIdx.x * 4;
  float4 g4[4];
#pragma unroll
  for (int g = 0; g < 4; g++) g4[g] = *(const float4*)(bvec + g * Dd + dc);
#pragma unroll 8
  for (int ds = 0; ds < GDS; ds++) {
#pragma unroll
    for (int g = 0; g < 4; g++) {
      float4 p = *(const float4*)(Gp + ((size_t)ds * BKn + bk) * Ff + g * Dd + dc);
      g4[g].x += p.x; g4[g].y += p.y; g4[g].z += p.z; g4[g].w += p.w;
    }
  }
  int src = (bk & ~3) | wsi[IPREV + bk];
  float4 c4 = *(const float4*)(cPrev + (size_t)src * Dd + dc);
  float ci[4] = {g4[0].x, g4[0].y, g4[0].z, g4[0].w};
  float cf[4] = {g4[1].x, g4[1].y, g4[1].z, g4[1].w};
  float cg[4] = {g4[2].x, g4[2].y, g4[2].z, g4[2].w};
  float co[4] = {g4[3].x, g4[3].y, g4[3].z, g4[3].w};
  float cv[4] = {c4.x, c4.y, c4.z, c4.w};
  float cn[4], hn[4];
#pragma unroll
  for (int j = 0; j < 4; j++) {
    float si = 1.f / (1.f + expf(-ci[j]));
    float sf = 1.f / (1.f + expf(-cf[j]));
    float so = 1.f / (1.f + expf(-co[j]));
    float tg = tanhf(cg[j]);
    cn[j] = sf * cv[j] + si * tg;
    hn[j] = so * tanhf(cn[j]);
  }
  float4 cno = {cn[0], cn[1], cn[2], cn[3]};
  *(float4*)(cNew + (size_t)bk * Dd + dc) = cno;
#pragma unroll
  for (int j = 0; j < 4; j++) hTn[(size_t)(dc + j) * BKn + bk] = hn[j];
}

// logits partial GEMM. grid (125, 8): x = 256-col tile of v, y = d-chunk of 128.
// P layout: [ds][bg][32000][8 beams], so stores are contiguous 32B per (thread,col).
__global__ __launch_bounds__(256) void logitsK(const float* __restrict__ Wo,
    const float* __restrict__ hTn, float* __restrict__ P) {
  __shared__ float hs[LDC][BKn];
  int tid = threadIdx.x;
  int d0 = blockIdx.y * LDC;
  {
    int bk = tid & 31, dq = tid >> 5;
#pragma unroll
    for (int k = 0; k < 16; k++) {
      int d = dq * 16 + k;
      hs[d][bk] = hTn[(size_t)(d0 + d) * BKn + bk];
    }
  }
  __syncthreads();
  int ct = tid & 63, bg = tid >> 6;
  size_t v0 = (size_t)blockIdx.x * 256 + ct * 4;
  float acc[4][8];
#pragma unroll
  for (int c = 0; c < 4; c++)
#pragma unroll
    for (int i = 0; i < 8; i++) acc[c][i] = 0.f;
#pragma unroll 4
  for (int d = 0; d < LDC; ++d) {
    float4 w = *(const float4*)(Wo + (size_t)(d0 + d) * Vv + v0);
    float4 hlo = *(const float4*)&hs[d][bg * 8];
    float4 hhi = *(const float4*)&hs[d][bg * 8 + 4];
    float hv[8] = {hlo.x, hlo.y, hlo.z, hlo.w, hhi.x, hhi.y, hhi.z, hhi.w};
    float wc[4] = {w.x, w.y, w.z, w.w};
#pragma unroll
    for (int c = 0; c < 4; c++)
#pragma unroll
      for (int i = 0; i < 8; i++)
        acc[c][i] = fmaf(hv[i], wc[c], acc[c][i]);
  }
  float* base = P + ((size_t)(blockIdx.y * 4 + bg) * Vv) * 8;
#pragma unroll
  for (int c = 0; c < 4; c++) {
    float4 lo = {acc[c][0], acc[c][1], acc[c][2], acc[c][3]};
    float4 hi = {acc[c][4], acc[c][5], acc[c][6], acc[c][7]};
    *(float4*)(base + (v0 + c) * 8) = lo;
    *(float4*)(base + (v0 + c) * 8 + 4) = hi;
  }
}

// reduce 8 logit partials + bias -> full logits in LDS -> chunk stats (max/sumexp/top4).
// grid 250 blocks x 256 threads; block = 128 vocab cols.
__global__ __launch_bounds__(256) void logitsRedK(const float* __restrict__ P,
    const float* __restrict__ bo, float* __restrict__ cs) {
  __shared__ float sd[BKn][128];
  int tid = threadIdx.x;
  int vl = tid & 127, bh = tid >> 7;     // bh: beam half (16 beams each)
  size_t v = (size_t)blockIdx.x * 128 + vl;
  float b = bo[v];
#pragma unroll
  for (int bgl = 0; bgl < 2; bgl++) {
    int bg = bh * 2 + bgl;
    float4 lo = {0, 0, 0, 0}, hi = {0, 0, 0, 0};
#pragma unroll
    for (int ds = 0; ds < LDSP; ds++) {
      const float* p = P + ((size_t)(ds * 4 + bg) * Vv + v) * 8;
      float4 a = *(const float4*)p;
      float4 c = *(const float4*)(p + 4);
      lo.x += a.x; lo.y += a.y; lo.z += a.z; lo.w += a.w;
      hi.x += c.x; hi.y += c.y; hi.z += c.z; hi.w += c.w;
    }
    int bk0 = bg * 8;
    sd[bk0 + 0][vl] = lo.x + b; sd[bk0 + 1][vl] = lo.y + b;
    sd[bk0 + 2][vl] = lo.z + b; sd[bk0 + 3][vl] = lo.w + b;
    sd[bk0 + 4][vl] = hi.x + b; sd[bk0 + 5][vl] = hi.y + b;
    sd[bk0 + 6][vl] = hi.z + b; sd[bk0 + 7][vl] = hi.w + b;
  }
  __syncthreads();
  if (tid >= 128) return;
  int lane = tid & 63;
  int wv_ = tid >> 6;
  int i0 = blockIdx.x * 128 + lane;
  int i1 = i0 + 64;
  for (int bb = 0; bb < 16; ++bb) {
    int bk = wv_ * 16 + bb;
    float v0f = sd[bk][lane];
    float v1f = sd[bk][lane + 64];
    float m = fmaxf(v0f, v1f);
    for (int off = 32; off; off >>= 1) m = fmaxf(m, __shfl_xor(m, off));
    float se = expf(v0f - m) + expf(v1f - m);
    for (int off = 32; off; off >>= 1) se += __shfl_xor(se, off);
    float tv[4]; int ti[4];
#pragma unroll
    for (int r = 0; r < 4; r++) { tv[r] = -FLT_MAX; ti[r] = 0x7fffffff; }
    ins4(v0f, i0, tv, ti);
    ins4(v1f, i1, tv, ti);
    float ov[4]; int oi[4];
    merge_top4<32>(tv, ti, ov, oi);
    if (lane == 0) {
      float* p = cs + ((size_t)blockIdx.x * BKn + bk) * 12;
      p[0] = m; p[1] = se;
#pragma unroll
      for (int r = 0; r < 4; r++) { p[2 + r] = ov[r]; p[6 + r] = __int_as_float(oi[r]); }
    }
  }
}

// fused: per-beam merge of 250 chunk stats -> lse + top4; then exact selection,
// EOS logic, buf ping-pong. One block of 1024 threads.
__global__ __launch_bounds__(1024) void redSelK(float* __restrict__ ws, int step) {
  __shared__ float bt_s[BKn][8];
  __shared__ int s_tok[BKn], s_prevb[BKn];
  int* wsi = (int*)(ws + OFF_INT);
  const float* cs = ws + OFF_CS;
  int tid = threadIdx.x;
  int wv = tid >> 6, lane = tid & 63;
  {
    int half = lane >> 5, l32 = lane & 31;
    int bk = wv * 2 + half;                 // 16 waves x 2 halves = 32 beams
    float tv[4]; int ti[4];
#pragma unroll
    for (int r = 0; r < 4; r++) { tv[r] = -FLT_MAX; ti[r] = 0x7fffffff; }
    float cm[8], csum[8]; bool val[8];
    float lm = -FLT_MAX;
#pragma unroll
    for (int q = 0; q < 8; q++) {
      int c = l32 + 32 * q;
      val[q] = c < NVCH;
      if (val[q]) {
        const float* p = cs + ((size_t)c * BKn + bk) * 12;
        cm[q] = p[0]; csum[q] = p[1];
        lm = fmaxf(lm, cm[q]);
#pragma unroll
        for (int r = 0; r < 4; r++) ins4(p[2 + r], __float_as_int(p[6 + r]), tv, ti);
      } else { cm[q] = -FLT_MAX; csum[q] = 0.f; }
    }
    float M = lm;
    for (int off = 16; off; off >>= 1) M = fmaxf(M, __shfl_xor(M, off));
    float ls = 0.f;
#pragma unroll
    for (int q = 0; q < 8; q++) if (val[q]) ls += csum[q] * expf(cm[q] - M);
    for (int off = 16; off; off >>= 1) ls += __shfl_xor(ls, off);
    float lse = M + logf(ls);
    float ov[4]; int oi[4];
    merge_top4<16>(tv, ti, ov, oi);
    if (l32 == 0) {
#pragma unroll
      for (int r = 0; r < 4; r++) {
        bt_s[bk][r] = lse - ov[r];
        bt_s[bk][4 + r] = __int_as_float(oi[r]);
      }
    }
  }
  __syncthreads();
  if (tid < Bb) {
    int b = tid;
    int st = wsi[ISTOP + b];
    float sc[4];
#pragma unroll
    for (int k = 0; k < 4; k++) sc[k] = ws[OFF_SC + b * 4 + k];
    float cval[16]; int ctok[16];
#pragma unroll
    for (int kb = 0; kb < 4; kb++)
#pragma unroll
      for (int r = 0; r < 4; r++) {
        cval[kb * 4 + r] = bt_s[b * 4 + kb][r] + sc[kb];
        ctok[kb * 4 + r] = __float_as_int(bt_s[b * 4 + kb][4 + r]);
      }
    float selS[4]; int selW[4], prevK[4];
    int usedMask = 0;
#pragma unroll
    for (int r = 0; r < 4; r++) {
      int best = -1; float bv = FLT_MAX;
#pragma unroll
      for (int t = 0; t < 16; t++) {
        if (!((usedMask >> t) & 1) && cval[t] < bv) { bv = cval[t]; best = t; }
      }
      usedMask |= 1 << best;
      selS[r] = bv; selW[r] = ctok[best]; prevK[r] = best >> 2;
    }
    bool eos[4];
#pragma unroll
    for (int r = 0; r < 4; r++) eos[r] = (selW[r] == EOSt);
    bool first = eos[0] && !st;
#pragma unroll
    for (int r = 0; r < 4; r++) if (eos[r] && !first && !st) selS[r] = EOSSf;
#pragma unroll
    for (int k = 0; k < 4; k++) {
      int tok = st ? PADt : (first ? EOSt : selW[k]);
      int pb  = st ? k : prevK[k];
      s_tok[b * 4 + k] = tok;
      s_prevb[b * 4 + k] = pb;
      if (!st) { ws[OFF_SC + b * 4 + k] = selS[k]; wsi[IW + b * 4 + k] = selW[k]; }
      wsi[IPREV + b * 4 + k] = prevK[k];
    }
    wsi[ISTOP + b] = (st || first) ? 1 : 0;
  }
  __syncthreads();
  if (tid < 512) {
    const int* br = wsi + (((step & 1) == 0) ? IBUFA : IBUFB);
    int* bw = wsi + (((step & 1) == 0) ? IBUFB : IBUFA);
    int bkk = tid >> 4, t = tid & 15;
    int pb = s_prevb[bkk];
    int src = ((bkk & ~3) | pb) * Tt + t;
    int val = br[src];
    if (t == step) val = s_tok[bkk];
    bw[tid] = val;
  }
}

// Output read as float32 by harness: tokens as float values, scores as floats.
__global__ __launch_bounds__(256) void outK(const float* __restrict__ ws,
                                            float* __restrict__ out) {
  const int* wsi = (const int*)(ws + OFF_INT);
  int g = blockIdx.x * 256 + threadIdx.x;
  if (g < Bb * Kk * Tt) {
    out[g] = (float)wsi[IBUFA + g];               // final buf in A after 16 steps
  } else if (g < Bb * Kk * Tt + BKn) {
    out[g] = ws[OFF_SC + (g - Bb * Kk * Tt)];
  }
}

} // namespace

extern "C" void kernel_launch(void* const* d_in, const int* in_sizes, int n_in,
                              void* d_out, int out_size, void* d_ws, size_t ws_size,
                              hipStream_t stream) {
  (void)in_sizes; (void)n_in; (void)out_size; (void)ws_size;
  const int*   words = (const int*)d_in[0];
  const float* h0 = (const float*)d_in[1];
  const float* c0 = (const float*)d_in[2];
  const float* E  = (const float*)d_in[3];
  const float* Wx = (const float*)d_in[4];
  const float* Wh = (const float*)d_in[5];
  const float* bv = (const float*)d_in[6];
  const float* Wo = (const float*)d_in[7];
  const float* bo = (const float*)d_in[8];
  float* ws = (float*)d_ws;
  float* hTn = ws + OFF_HTN;
  float* cb0 = ws + OFF_CB0;
  float* cb1 = ws + OFF_CB1;
  float* Gp  = ws + OFF_GP;
  float* P   = ws + OFF_PL;
  float* cs  = ws + OFF_CS;
  int*   wsi = (int*)(ws + OFF_INT);

  initK<<<129, 256, 0, stream>>>(words, h0, c0, ws);
  for (int j = 0; j < Tt; j++) {
    float* cPrev = (j & 1) ? cb1 : cb0;
    float* cNext = (j & 1) ? cb0 : cb1;
    gatesK<<<dim3(16, GDS), 256, 0, stream>>>(Wx, Wh, E, hTn, wsi, Gp);
    lstmK<<<dim3(32, 4), 64, 0, stream>>>(bv, Gp, cPrev, wsi, cNext, hTn);
    logitsK<<<dim3(125, LDSP), 256, 0, stream>>>(Wo, hTn, P);
    logitsRedK<<<NVCH, 256, 0, stream>>>(P, bo, cs);
    redSelK<<<1, 1024, 0, stream>>>(ws, j);
  }
  outK<<<3, 256, 0, stream>>>(ws, (float*)d_out);
}